// Round 2
// baseline (1011.972 us; speedup 1.0000x reference)
//
#include <hip/hip_runtime.h>
#include <hip/hip_bf16.h>

#define S_LEN 4096
#define NH 16
#define HD 64
#define DIM 1024
#define NQKV 3072

typedef __attribute__((ext_vector_type(8))) short short8;
typedef __attribute__((ext_vector_type(4))) float floatx4;
typedef __attribute__((ext_vector_type(4))) float float4v;

static __device__ __forceinline__ float bf16_to_f32(ushort u) {
    return __uint_as_float(((unsigned int)u) << 16);
}
static __device__ __forceinline__ ushort f32_to_bf16(float f) {
    __hip_bfloat16 b = __float2bfloat16(f);
    return *(ushort*)&b;
}

// ---------------- dtype detector: f32-as-ushort has random exp fields ----------------
__global__ void detect_k(const ushort* __restrict__ x, int* __restrict__ flag) {
    __shared__ int cnt;
    if (threadIdx.x == 0) cnt = 0;
    __syncthreads();
    int c = 0;
    for (int i = threadIdx.x; i < 65536; i += 256) {
        ushort u = x[i];
        if (((u >> 7) & 0xFF) == 0xFF) c++;   // Inf/NaN bf16 pattern
    }
    atomicAdd(&cnt, c);
    __syncthreads();
    if (threadIdx.x == 0) *flag = (cnt > 8) ? 1 : 0;   // 1 => inputs are float32
}

// ---------------- convert x to bf16 (flag-aware), 8 elems/thread ----------------
__global__ __launch_bounds__(256) void convert_x(const void* __restrict__ src,
                                                 ushort* __restrict__ dst,
                                                 const int* __restrict__ flag) {
    const int f = *flag;
    const size_t t = (size_t)blockIdx.x * 256 + threadIdx.x;   // 524288 threads
    const size_t base = t * 8;
    if (f) {
        const float4v* s = (const float4v*)((const float*)src + base);
        float4v a = s[0], b = s[1];
        ushort o[8];
        o[0]=f32_to_bf16(a[0]); o[1]=f32_to_bf16(a[1]); o[2]=f32_to_bf16(a[2]); o[3]=f32_to_bf16(a[3]);
        o[4]=f32_to_bf16(b[0]); o[5]=f32_to_bf16(b[1]); o[6]=f32_to_bf16(b[2]); o[7]=f32_to_bf16(b[3]);
        *(short8*)(dst + base) = *(short8*)o;
    } else {
        *(short8*)(dst + base) = *(const short8*)((const ushort*)src + base);
    }
}

// ---------------- fused convert + transpose: src[rows,cols] -> dst[cols,rows] bf16 ----------------
__global__ void convt_k(const void* __restrict__ src, ushort* __restrict__ dst,
                        int rows, int cols, const int* __restrict__ flag) {
    __shared__ ushort tile[32][33];
    const int f = *flag;
    int bx = blockIdx.x * 32;   // col base
    int by = blockIdx.y * 32;   // row base
    int tx = threadIdx.x & 31, ty = threadIdx.x >> 5;
    if (f) {
        const float* s = (const float*)src;
#pragma unroll
        for (int r = ty; r < 32; r += 8)
            tile[r][tx] = f32_to_bf16(s[(size_t)(by + r) * cols + bx + tx]);
    } else {
        const ushort* s = (const ushort*)src;
#pragma unroll
        for (int r = ty; r < 32; r += 8)
            tile[r][tx] = s[(size_t)(by + r) * cols + bx + tx];
    }
    __syncthreads();
#pragma unroll
    for (int r = ty; r < 32; r += 8)
        dst[(size_t)(bx + r) * rows + by + tx] = tile[tx][r];
}

// ---------------- GEMM: C[M,N] = A[M,K] @ Bt[N,K]^T, bf16 in, fp32 acc ----------------
// mode 0: scatter bf16 into qkv as [3][NH][S][HD]; mode 1: write output (f32 or bf16 per flag)
__global__ __launch_bounds__(256) void gemm_tn(const ushort* __restrict__ A,
                                               const ushort* __restrict__ Bt,
                                               void* __restrict__ out,
                                               int M, int N, int K, int mode,
                                               const int* __restrict__ flag) {
    __shared__ ushort As[128 * 40];
    __shared__ ushort Bs[128 * 40];

    const int outf = (mode == 1) ? *flag : 0;

    const int tid  = threadIdx.x;
    const int lane = tid & 63;
    const int wave = tid >> 6;
    const int wr = wave >> 1, wc = wave & 1;
    const int rowBase = blockIdx.y * 128;
    const int colBase = blockIdx.x * 128;

    floatx4 acc[4][4];
#pragma unroll
    for (int mi = 0; mi < 4; mi++)
#pragma unroll
        for (int ni = 0; ni < 4; ni++)
            acc[mi][ni] = (floatx4){0.f, 0.f, 0.f, 0.f};

    const int sRow = tid >> 1;
    const int sK   = (tid & 1) * 16;
    const ushort* aPtr = A  + (size_t)(rowBase + sRow) * K + sK;
    const ushort* bPtr = Bt + (size_t)(colBase + sRow) * K + sK;

    const int qk = (lane >> 4) * 8;
    const int fr = lane & 15;

    for (int k0 = 0; k0 < K; k0 += 32) {
        short8 a0 = *(const short8*)(aPtr + k0);
        short8 a1 = *(const short8*)(aPtr + k0 + 8);
        short8 b0 = *(const short8*)(bPtr + k0);
        short8 b1 = *(const short8*)(bPtr + k0 + 8);
        *(short8*)&As[sRow * 40 + sK]     = a0;
        *(short8*)&As[sRow * 40 + sK + 8] = a1;
        *(short8*)&Bs[sRow * 40 + sK]     = b0;
        *(short8*)&Bs[sRow * 40 + sK + 8] = b1;
        __syncthreads();

        short8 af[4], bfr[4];
#pragma unroll
        for (int mi = 0; mi < 4; mi++)
            af[mi] = *(const short8*)&As[(wr * 64 + mi * 16 + fr) * 40 + qk];
#pragma unroll
        for (int ni = 0; ni < 4; ni++)
            bfr[ni] = *(const short8*)&Bs[(wc * 64 + ni * 16 + fr) * 40 + qk];

#pragma unroll
        for (int mi = 0; mi < 4; mi++)
#pragma unroll
            for (int ni = 0; ni < 4; ni++)
                acc[mi][ni] = __builtin_amdgcn_mfma_f32_16x16x32_bf16(
                    af[mi], bfr[ni], acc[mi][ni], 0, 0, 0);
        __syncthreads();
    }

    const int qr = (lane >> 4) * 4;
#pragma unroll
    for (int mi = 0; mi < 4; mi++) {
#pragma unroll
        for (int ni = 0; ni < 4; ni++) {
            const int c = colBase + wc * 64 + ni * 16 + fr;
#pragma unroll
            for (int r = 0; r < 4; r++) {
                const int srow = rowBase + wr * 64 + mi * 16 + qr + r;
                const float v = acc[mi][ni][r];
                if (mode == 0) {
                    const int part = c >> 10;
                    const int rem  = c & 1023;
                    const int hh   = rem >> 6;
                    const int dd   = rem & 63;
                    ((ushort*)out)[((size_t)part * NH + hh) * S_LEN * HD +
                                   (size_t)srow * HD + dd] = f32_to_bf16(v);
                } else if (outf) {
                    ((float*)out)[(size_t)srow * N + c] = v;
                } else {
                    ((ushort*)out)[(size_t)srow * N + c] = f32_to_bf16(v);
                }
            }
        }
    }
}

// ---------------- sparse attention: one wave per (head, query), lanes = dims ----------------
__global__ __launch_bounds__(256) void attn_k(const ushort* __restrict__ qkv,
                                              ushort* __restrict__ attnout) {
    const int gtid = blockIdx.x * 256 + threadIdx.x;
    const int wid  = gtid >> 6;
    const int lane = gtid & 63;
    const int i = wid & (S_LEN - 1);
    const int h = wid >> 12;

    const ushort* Qp = qkv;
    const ushort* Kp = qkv + (size_t)NH * S_LEN * HD;
    const ushort* Vp = qkv + (size_t)2 * NH * S_LEN * HD;
    const size_t hb = (size_t)h * S_LEN * HD;

    const float q = bf16_to_f32(Qp[hb + (size_t)i * HD + lane]);
    const float scale = 0.125f;   // 1/sqrt(64)

    float lsum = 0.f, acc = 0.f;

    int lo   = i - 128; if (lo < 0) lo = 0;
    int gEnd = lo < 64 ? lo : 64;

    auto doKey = [&](int j) {
        float kv = bf16_to_f32(Kp[hb + (size_t)j * HD + lane]);
        float s = q * kv;
#pragma unroll
        for (int m = 32; m > 0; m >>= 1) s += __shfl_xor(s, m, 64);
        s *= scale;
        s = fminf(s, 60.f);
        float p = __expf(s);
        lsum += p;
        float vv = bf16_to_f32(Vp[hb + (size_t)j * HD + lane]);
        acc += p * vv;
    };

    for (int j = 0; j < gEnd; ++j) doKey(j);   // global tokens not in band
    for (int j = lo; j <= i; ++j) doKey(j);    // causal local band

    attnout[(size_t)i * DIM + h * HD + lane] = f32_to_bf16(acc / lsum);
}

// ---------------- launch ----------------
extern "C" void kernel_launch(void* const* d_in, const int* in_sizes, int n_in,
                              void* d_out, int out_size, void* d_ws, size_t ws_size,
                              hipStream_t stream) {
    const void* x    = d_in[0];   // [S, DIM]        (f32 or bf16)
    const void* wqkv = d_in[1];   // [DIM, 3*NH*HD]
    const void* wout = d_in[2];   // [DIM, DIM]

    ushort* ws    = (ushort*)d_ws;
    ushort* xb    = ws;                                   // [S, DIM] bf16
    ushort* wqkvT = xb + (size_t)S_LEN * DIM;             // [NQKV, DIM]
    ushort* woutT = wqkvT + (size_t)NQKV * DIM;           // [DIM, DIM]
    ushort* qkv   = woutT + (size_t)DIM * DIM;            // [3][NH][S][HD]
    ushort* attno = qkv + (size_t)3 * NH * S_LEN * HD;    // [S, DIM]
    int* flagp    = (int*)(attno + (size_t)S_LEN * DIM);

    detect_k<<<1, 256, 0, stream>>>((const ushort*)x, flagp);

    convert_x<<<(S_LEN * DIM / 8 + 255) / 256, 256, 0, stream>>>(x, xb, flagp);
    convt_k<<<dim3(NQKV / 32, DIM / 32), 256, 0, stream>>>(wqkv, wqkvT, DIM, NQKV, flagp);
    convt_k<<<dim3(DIM / 32, DIM / 32), 256, 0, stream>>>(wout, woutT, DIM, DIM, flagp);

    gemm_tn<<<dim3(NQKV / 128, S_LEN / 128), 256, 0, stream>>>(xb, wqkvT, qkv,
                                                               S_LEN, NQKV, DIM, 0, flagp);

    attn_k<<<dim3(S_LEN * NH / 4), 256, 0, stream>>>(qkv, attno);

    gemm_tn<<<dim3(DIM / 128, S_LEN / 128), 256, 0, stream>>>(attno, woutT, d_out,
                                                              S_LEN, DIM, DIM, 1, flagp);
}

// Round 3
// 238.681 us; speedup vs baseline: 4.2398x; 4.2398x over previous
//
#include <hip/hip_runtime.h>
#include <hip/hip_bf16.h>

#define S_LEN 4096
#define NH 16
#define HD 64
#define DIM 1024
#define NQKV 3072

typedef __attribute__((ext_vector_type(8))) short short8;
typedef __attribute__((ext_vector_type(4))) float floatx4;
typedef __attribute__((ext_vector_type(4))) float float4v;

static __device__ __forceinline__ float bf16_to_f32(ushort u) {
    return __uint_as_float(((unsigned int)u) << 16);
}
static __device__ __forceinline__ ushort f32_to_bf16(float f) {
    __hip_bfloat16 b = __float2bfloat16(f);
    return *(ushort*)&b;
}

// ---------------- dtype detector: f32-as-ushort has random exp fields ----------------
__global__ void detect_k(const ushort* __restrict__ x, int* __restrict__ flag) {
    __shared__ int cnt;
    if (threadIdx.x == 0) cnt = 0;
    __syncthreads();
    int c = 0;
    for (int i = threadIdx.x; i < 65536; i += 256) {
        ushort u = x[i];
        if (((u >> 7) & 0xFF) == 0xFF) c++;   // Inf/NaN bf16 pattern
    }
    atomicAdd(&cnt, c);
    __syncthreads();
    if (threadIdx.x == 0) *flag = (cnt > 8) ? 1 : 0;   // 1 => inputs are float32
}

// ---------------- convert x to bf16 (flag-aware), 8 elems/thread ----------------
__global__ __launch_bounds__(256) void convert_x(const void* __restrict__ src,
                                                 ushort* __restrict__ dst,
                                                 const int* __restrict__ flag) {
    const int f = *flag;
    const size_t t = (size_t)blockIdx.x * 256 + threadIdx.x;
    const size_t base = t * 8;
    if (f) {
        const float4v* s = (const float4v*)((const float*)src + base);
        float4v a = s[0], b = s[1];
        ushort o[8];
        o[0]=f32_to_bf16(a[0]); o[1]=f32_to_bf16(a[1]); o[2]=f32_to_bf16(a[2]); o[3]=f32_to_bf16(a[3]);
        o[4]=f32_to_bf16(b[0]); o[5]=f32_to_bf16(b[1]); o[6]=f32_to_bf16(b[2]); o[7]=f32_to_bf16(b[3]);
        *(short8*)(dst + base) = *(short8*)o;
    } else {
        *(short8*)(dst + base) = *(const short8*)((const ushort*)src + base);
    }
}

// ---------------- fused convert + transpose: src[rows,cols] -> dst[cols,rows] bf16 ----------------
__global__ void convt_k(const void* __restrict__ src, ushort* __restrict__ dst,
                        int rows, int cols, const int* __restrict__ flag) {
    __shared__ ushort tile[32][33];
    const int f = *flag;
    int bx = blockIdx.x * 32;
    int by = blockIdx.y * 32;
    int tx = threadIdx.x & 31, ty = threadIdx.x >> 5;
    if (f) {
        const float* s = (const float*)src;
#pragma unroll
        for (int r = ty; r < 32; r += 8)
            tile[r][tx] = f32_to_bf16(s[(size_t)(by + r) * cols + bx + tx]);
    } else {
        const ushort* s = (const ushort*)src;
#pragma unroll
        for (int r = ty; r < 32; r += 8)
            tile[r][tx] = s[(size_t)(by + r) * cols + bx + tx];
    }
    __syncthreads();
#pragma unroll
    for (int r = ty; r < 32; r += 8)
        dst[(size_t)(bx + r) * rows + by + tx] = tile[tx][r];
}

// ---------------- per-head V transpose: V[h][s][d] -> Vt[h][d][s] ----------------
__global__ void transpose_v_k(const ushort* __restrict__ V, ushort* __restrict__ Vt) {
    __shared__ ushort tile[32][33];
    const int h  = blockIdx.z;
    const int s0 = blockIdx.y * 32;
    const int d0 = blockIdx.x * 32;
    int tx = threadIdx.x & 31, ty = threadIdx.x >> 5;
    const ushort* Vh  = V  + (size_t)h * S_LEN * HD;
    ushort*       Vth = Vt + (size_t)h * HD * S_LEN;
#pragma unroll
    for (int r = ty; r < 32; r += 8)
        tile[r][tx] = Vh[(size_t)(s0 + r) * HD + d0 + tx];
    __syncthreads();
#pragma unroll
    for (int r = ty; r < 32; r += 8)
        Vth[(size_t)(d0 + r) * S_LEN + s0 + tx] = tile[tx][r];
}

// ---------------- GEMM: C[M,N] = A[M,K] @ Bt[N,K]^T, bf16 in, fp32 acc ----------------
__global__ __launch_bounds__(256) void gemm_tn(const ushort* __restrict__ A,
                                               const ushort* __restrict__ Bt,
                                               void* __restrict__ out,
                                               int M, int N, int K, int mode,
                                               const int* __restrict__ flag) {
    __shared__ ushort As[128 * 40];
    __shared__ ushort Bs[128 * 40];

    const int outf = (mode == 1) ? *flag : 0;

    const int tid  = threadIdx.x;
    const int lane = tid & 63;
    const int wave = tid >> 6;
    const int wr = wave >> 1, wc = wave & 1;
    const int rowBase = blockIdx.y * 128;
    const int colBase = blockIdx.x * 128;

    floatx4 acc[4][4];
#pragma unroll
    for (int mi = 0; mi < 4; mi++)
#pragma unroll
        for (int ni = 0; ni < 4; ni++)
            acc[mi][ni] = (floatx4){0.f, 0.f, 0.f, 0.f};

    const int sRow = tid >> 1;
    const int sK   = (tid & 1) * 16;
    const ushort* aPtr = A  + (size_t)(rowBase + sRow) * K + sK;
    const ushort* bPtr = Bt + (size_t)(colBase + sRow) * K + sK;

    const int qk = (lane >> 4) * 8;
    const int fr = lane & 15;

    for (int k0 = 0; k0 < K; k0 += 32) {
        short8 a0 = *(const short8*)(aPtr + k0);
        short8 a1 = *(const short8*)(aPtr + k0 + 8);
        short8 b0 = *(const short8*)(bPtr + k0);
        short8 b1 = *(const short8*)(bPtr + k0 + 8);
        *(short8*)&As[sRow * 40 + sK]     = a0;
        *(short8*)&As[sRow * 40 + sK + 8] = a1;
        *(short8*)&Bs[sRow * 40 + sK]     = b0;
        *(short8*)&Bs[sRow * 40 + sK + 8] = b1;
        __syncthreads();

        short8 af[4], bfr[4];
#pragma unroll
        for (int mi = 0; mi < 4; mi++)
            af[mi] = *(const short8*)&As[(wr * 64 + mi * 16 + fr) * 40 + qk];
#pragma unroll
        for (int ni = 0; ni < 4; ni++)
            bfr[ni] = *(const short8*)&Bs[(wc * 64 + ni * 16 + fr) * 40 + qk];

#pragma unroll
        for (int mi = 0; mi < 4; mi++)
#pragma unroll
            for (int ni = 0; ni < 4; ni++)
                acc[mi][ni] = __builtin_amdgcn_mfma_f32_16x16x32_bf16(
                    af[mi], bfr[ni], acc[mi][ni], 0, 0, 0);
        __syncthreads();
    }

    const int qr = (lane >> 4) * 4;
#pragma unroll
    for (int mi = 0; mi < 4; mi++) {
#pragma unroll
        for (int ni = 0; ni < 4; ni++) {
            const int c = colBase + wc * 64 + ni * 16 + fr;
#pragma unroll
            for (int r = 0; r < 4; r++) {
                const int srow = rowBase + wr * 64 + mi * 16 + qr + r;
                const float v = acc[mi][ni][r];
                if (mode == 0) {
                    const int part = c >> 10;
                    const int rem  = c & 1023;
                    const int hh   = rem >> 6;
                    const int dd   = rem & 63;
                    ((ushort*)out)[((size_t)part * NH + hh) * S_LEN * HD +
                                   (size_t)srow * HD + dd] = f32_to_bf16(v);
                } else if (outf) {
                    ((float*)out)[(size_t)srow * N + c] = v;
                } else {
                    ((ushort*)out)[(size_t)srow * N + c] = f32_to_bf16(v);
                }
            }
        }
    }
}

// ---------------- MFMA block-sparse flash attention ----------------
// One WG per (head, 64-query tile). 4 waves, each owns 16 q-rows.
// Key blocks for tile qb: {0} ∪ {max(64,qb-128) .. qb step 64}  (<=4 blocks of 64).
#define PLD 72   // LDS leading dim for P (16 rows), 16B-aligned rows, conflict-light
__global__ __launch_bounds__(256) void attn_flash_k(const ushort* __restrict__ qkv,
                                                    const ushort* __restrict__ Vt,
                                                    ushort* __restrict__ attnout) {
    __shared__ ushort Plds[4][16 * PLD];

    const int wg   = blockIdx.x;        // 0..1023
    const int h    = wg >> 6;
    const int qb   = (wg & 63) * 64;
    const int wave = threadIdx.x >> 6;
    const int lane = threadIdx.x & 63;
    const int g    = lane >> 4;         // 0..3
    const int c    = lane & 15;         // 0..15

    const ushort* Qh  = qkv + (size_t)h * S_LEN * HD;
    const ushort* Kh  = qkv + (size_t)(NH + h) * S_LEN * HD;
    const ushort* Vth = Vt  + (size_t)h * HD * S_LEN;

    const int qrow0 = qb + wave * 16;

    // Q A-fragments, held in registers: m=c (q row within 16), k = 32*ks + g*8 + j
    short8 qf[2];
    qf[0] = *(const short8*)(Qh + (size_t)(qrow0 + c) * HD + g * 8);
    qf[1] = *(const short8*)(Qh + (size_t)(qrow0 + c) * HD + 32 + g * 8);

    floatx4 Oacc[4];                    // dim-tiles; col(dim)=16*nd+c, row(q)=g*4+r
#pragma unroll
    for (int nd = 0; nd < 4; nd++) Oacc[nd] = (floatx4){0.f, 0.f, 0.f, 0.f};
    float mrow[4] = {-1e30f, -1e30f, -1e30f, -1e30f};
    float lrow[4] = {0.f, 0.f, 0.f, 0.f};

    int blist[4];
    int nb = 0;
    blist[nb++] = 0;                    // global block first (always fully row-valid)
    int kbs = qb - 128; if (kbs < 64) kbs = 64;
    for (int kb = kbs; kb <= qb; kb += 64) blist[nb++] = kb;

    ushort* pl = &Plds[wave][0];

    for (int ib = 0; ib < nb; ib++) {
        const int kb = blist[ib];

        // ---- QK^T: scores for 16 q-rows x 64 keys ----
        floatx4 sc[4];
#pragma unroll
        for (int t = 0; t < 4; t++) sc[t] = (floatx4){0.f, 0.f, 0.f, 0.f};
#pragma unroll
        for (int ks = 0; ks < 2; ks++) {
#pragma unroll
            for (int t = 0; t < 4; t++) {
                short8 kf = *(const short8*)(Kh + (size_t)(kb + 16 * t + c) * HD + ks * 32 + g * 8);
                sc[t] = __builtin_amdgcn_mfma_f32_16x16x32_bf16(qf[ks], kf, sc[t], 0, 0, 0);
            }
        }

        // ---- mask + scale ----
#pragma unroll
        for (int t = 0; t < 4; t++) {
            const int j = kb + 16 * t + c;
#pragma unroll
            for (int r = 0; r < 4; r++) {
                const int qi = qrow0 + g * 4 + r;
                const bool ok = (j <= qi) && ((j >= qi - 128) || (j < 64));
                sc[t][r] = ok ? sc[t][r] * 0.125f : -1e30f;
            }
        }

        // ---- online softmax (row-wise over 64 keys; 16-lane group reduce) ----
#pragma unroll
        for (int r = 0; r < 4; r++) {
            float mx = fmaxf(fmaxf(sc[0][r], sc[1][r]), fmaxf(sc[2][r], sc[3][r]));
#pragma unroll
            for (int msk = 1; msk < 16; msk <<= 1) mx = fmaxf(mx, __shfl_xor(mx, msk, 64));
            const float mnew  = fmaxf(mrow[r], mx);
            const float alpha = __expf(mrow[r] - mnew);
            float psum = 0.f;
#pragma unroll
            for (int t = 0; t < 4; t++) {
                const float p = __expf(sc[t][r] - mnew);
                sc[t][r] = p;
                psum += p;
            }
#pragma unroll
            for (int msk = 1; msk < 16; msk <<= 1) psum += __shfl_xor(psum, msk, 64);
            lrow[r] = lrow[r] * alpha + psum;
            mrow[r] = mnew;
#pragma unroll
            for (int nd = 0; nd < 4; nd++) Oacc[nd][r] *= alpha;
        }

        // ---- P (C-layout) -> LDS -> A-layout ----
#pragma unroll
        for (int t = 0; t < 4; t++)
#pragma unroll
            for (int r = 0; r < 4; r++)
                pl[(g * 4 + r) * PLD + 16 * t + c] = f32_to_bf16(sc[t][r]);
        __syncthreads();

        // ---- PV: O += P @ V  (B-frags from pre-transposed Vt, contiguous) ----
#pragma unroll
        for (int ks = 0; ks < 2; ks++) {
            short8 pf = *(const short8*)(pl + c * PLD + ks * 32 + g * 8);
#pragma unroll
            for (int nd = 0; nd < 4; nd++) {
                short8 vf = *(const short8*)(Vth + (size_t)(16 * nd + c) * S_LEN + kb + ks * 32 + g * 8);
                Oacc[nd] = __builtin_amdgcn_mfma_f32_16x16x32_bf16(pf, vf, Oacc[nd], 0, 0, 0);
            }
        }
        __syncthreads();
    }

    // ---- normalize + store ----
#pragma unroll
    for (int r = 0; r < 4; r++) {
        const float inv = 1.0f / lrow[r];
        const int qi = qrow0 + g * 4 + r;
#pragma unroll
        for (int nd = 0; nd < 4; nd++)
            attnout[(size_t)qi * DIM + h * HD + 16 * nd + c] = f32_to_bf16(Oacc[nd][r] * inv);
    }
}

// ---------------- launch ----------------
extern "C" void kernel_launch(void* const* d_in, const int* in_sizes, int n_in,
                              void* d_out, int out_size, void* d_ws, size_t ws_size,
                              hipStream_t stream) {
    const void* x    = d_in[0];   // [S, DIM]
    const void* wqkv = d_in[1];   // [DIM, 3*NH*HD]
    const void* wout = d_in[2];   // [DIM, DIM]

    ushort* ws    = (ushort*)d_ws;
    ushort* xb    = ws;                                   // [S, DIM] bf16
    ushort* wqkvT = xb + (size_t)S_LEN * DIM;             // [NQKV, DIM]
    ushort* woutT = wqkvT + (size_t)NQKV * DIM;           // [DIM, DIM]
    ushort* qkv   = woutT + (size_t)DIM * DIM;            // [3][NH][S][HD]
    ushort* attno = qkv + (size_t)3 * NH * S_LEN * HD;    // [S, DIM]
    ushort* vt    = attno + (size_t)S_LEN * DIM;          // [NH][HD][S]
    int* flagp    = (int*)(vt + (size_t)NH * HD * S_LEN);

    detect_k<<<1, 256, 0, stream>>>((const ushort*)x, flagp);

    convert_x<<<(S_LEN * DIM / 8 + 255) / 256, 256, 0, stream>>>(x, xb, flagp);
    convt_k<<<dim3(NQKV / 32, DIM / 32), 256, 0, stream>>>(wqkv, wqkvT, DIM, NQKV, flagp);
    convt_k<<<dim3(DIM / 32, DIM / 32), 256, 0, stream>>>(wout, woutT, DIM, DIM, flagp);

    gemm_tn<<<dim3(NQKV / 128, S_LEN / 128), 256, 0, stream>>>(xb, wqkvT, qkv,
                                                               S_LEN, NQKV, DIM, 0, flagp);

    transpose_v_k<<<dim3(HD / 32, S_LEN / 32, NH), 256, 0, stream>>>(
        qkv + (size_t)2 * NH * S_LEN * HD, vt);

    attn_flash_k<<<dim3(NH * (S_LEN / 64)), 256, 0, stream>>>(qkv, vt, attno);

    gemm_tn<<<dim3(DIM / 128, S_LEN / 128), 256, 0, stream>>>(attno, woutT, d_out,
                                                              S_LEN, DIM, DIM, 1, flagp);
}

// Round 4
// 193.036 us; speedup vs baseline: 5.2424x; 1.2365x over previous
//
#include <hip/hip_runtime.h>
#include <hip/hip_bf16.h>

#define S_LEN 4096
#define NH 16
#define HD 64
#define DIM 1024
#define NQKV 3072

typedef __attribute__((ext_vector_type(8))) short short8;
typedef __attribute__((ext_vector_type(4))) float floatx4;
typedef __attribute__((ext_vector_type(4))) float float4v;
typedef __attribute__((ext_vector_type(4))) ushort ushort4v;

static __device__ __forceinline__ float bf16_to_f32(ushort u) {
    return __uint_as_float(((unsigned int)u) << 16);
}
static __device__ __forceinline__ ushort f32_to_bf16(float f) {
    __hip_bfloat16 b = __float2bfloat16(f);
    return *(ushort*)&b;
}

#define GLOAD_LDS16(g, l)                                                    \
    __builtin_amdgcn_global_load_lds(                                        \
        (const __attribute__((address_space(1))) void*)(g),                  \
        (__attribute__((address_space(3))) void*)(l), 16, 0, 0)

// ---------------- dtype detector: parallel, vectorized ----------------
// Scans first 65536 ushorts of x. f32 input => low half-words are random
// mantissa bits => ~128 bf16 Inf/NaN exponent patterns. bf16 N(0,1) => 0.
__global__ void detect_k(const ushort* __restrict__ x, int* __restrict__ cnt) {
    const int t = blockIdx.x * 256 + threadIdx.x;   // 16384 threads x 4 ushorts
    ushort4v v = *(const ushort4v*)(x + (size_t)t * 4);
    int c = 0;
#pragma unroll
    for (int i = 0; i < 4; i++)
        if (((v[i] >> 7) & 0xFF) == 0xFF) c++;
#pragma unroll
    for (int m = 32; m > 0; m >>= 1) c += __shfl_xor(c, m, 64);
    if ((threadIdx.x & 63) == 0 && c) atomicAdd(cnt, c);
}

// ---------------- convert x to bf16 (flag-aware), 8 elems/thread ----------------
__global__ __launch_bounds__(256) void convert_x(const void* __restrict__ src,
                                                 ushort* __restrict__ dst,
                                                 const int* __restrict__ cnt) {
    const int f = (*cnt > 8);
    const size_t t = (size_t)blockIdx.x * 256 + threadIdx.x;
    const size_t base = t * 8;
    if (f) {
        const float4v* s = (const float4v*)((const float*)src + base);
        float4v a = s[0], b = s[1];
        ushort o[8];
        o[0]=f32_to_bf16(a[0]); o[1]=f32_to_bf16(a[1]); o[2]=f32_to_bf16(a[2]); o[3]=f32_to_bf16(a[3]);
        o[4]=f32_to_bf16(b[0]); o[5]=f32_to_bf16(b[1]); o[6]=f32_to_bf16(b[2]); o[7]=f32_to_bf16(b[3]);
        *(short8*)(dst + base) = *(short8*)o;
    } else {
        *(short8*)(dst + base) = *(const short8*)((const ushort*)src + base);
    }
}

// ---------------- fused convert + transpose: src[rows,cols] -> dst[cols,rows] bf16 ----------------
__global__ void convt_k(const void* __restrict__ src, ushort* __restrict__ dst,
                        int rows, int cols, const int* __restrict__ cnt) {
    __shared__ ushort tile[32][33];
    const int f = (*cnt > 8);
    int bx = blockIdx.x * 32;
    int by = blockIdx.y * 32;
    int tx = threadIdx.x & 31, ty = threadIdx.x >> 5;
    if (f) {
        const float* s = (const float*)src;
#pragma unroll
        for (int r = ty; r < 32; r += 8)
            tile[r][tx] = f32_to_bf16(s[(size_t)(by + r) * cols + bx + tx]);
    } else {
        const ushort* s = (const ushort*)src;
#pragma unroll
        for (int r = ty; r < 32; r += 8)
            tile[r][tx] = s[(size_t)(by + r) * cols + bx + tx];
    }
    __syncthreads();
#pragma unroll
    for (int r = ty; r < 32; r += 8)
        dst[(size_t)(bx + r) * rows + by + tx] = tile[tx][r];
}

// ---------------- GEMM (m97-style): C[M,N] = A[M,K] @ Bt[N,K]^T ----------------
// global_load_lds width-16 staging into unpadded 128x32 tiles.
// mode 0: scatter Q,K into qkv[part][h][s][d]; V directly into vt[h][d][s].
// mode 1: write f32 or bf16 output per flag.
__global__ __launch_bounds__(256) void gemm_lds(const ushort* __restrict__ A,
                                                const ushort* __restrict__ Bt,
                                                void* __restrict__ out,
                                                ushort* __restrict__ vt,
                                                int M, int N, int K, int mode,
                                                const int* __restrict__ cnt) {
    __shared__ ushort As[128 * 32];
    __shared__ ushort Bs[128 * 32];

    const int outf = (mode == 1) ? (*cnt > 8) : 0;

    const int tid  = threadIdx.x;
    const int lane = tid & 63;
    const int wave = tid >> 6;
    const int wr = wave >> 1, wc = wave & 1;
    const int rowBase = blockIdx.y * 128;
    const int colBase = blockIdx.x * 128;

    floatx4 acc[4][4];
#pragma unroll
    for (int mi = 0; mi < 4; mi++)
#pragma unroll
        for (int ni = 0; ni < 4; ni++)
            acc[mi][ni] = (floatx4){0.f, 0.f, 0.f, 0.f};

    // staging: wave w, call i covers chunks (w*2+i)*64 + lane
    // chunk cid -> row = cid>>2 (0..127), kchunk = cid&3 (8 ushorts each)
    const int srow = lane >> 2;        // + (wave*2+i)*16
    const int skc  = (lane & 3) * 8;

    const int g  = lane >> 4;          // 0..3
    const int c  = lane & 15;          // 0..15
    const int qk = g * 8;

    for (int k0 = 0; k0 < K; k0 += 32) {
#pragma unroll
        for (int i = 0; i < 2; i++) {
            const int r0 = (wave * 2 + i) * 16;
            GLOAD_LDS16(A  + (size_t)(rowBase + r0 + srow) * K + k0 + skc,
                        &As[(size_t)(wave * 2 + i) * 512]);
            GLOAD_LDS16(Bt + (size_t)(colBase + r0 + srow) * K + k0 + skc,
                        &Bs[(size_t)(wave * 2 + i) * 512]);
        }
        __syncthreads();

        short8 af[4], bfr[4];
#pragma unroll
        for (int mi = 0; mi < 4; mi++)
            af[mi] = *(const short8*)&As[(wr * 64 + mi * 16 + c) * 32 + qk];
#pragma unroll
        for (int ni = 0; ni < 4; ni++)
            bfr[ni] = *(const short8*)&Bs[(wc * 64 + ni * 16 + c) * 32 + qk];

#pragma unroll
        for (int mi = 0; mi < 4; mi++)
#pragma unroll
            for (int ni = 0; ni < 4; ni++)
                acc[mi][ni] = __builtin_amdgcn_mfma_f32_16x16x32_bf16(
                    af[mi], bfr[ni], acc[mi][ni], 0, 0, 0);
        __syncthreads();
    }

    // epilogue: C/D layout col = lane&15, row = (lane>>4)*4 + r
    const int qr = g * 4;
#pragma unroll
    for (int mi = 0; mi < 4; mi++) {
#pragma unroll
        for (int ni = 0; ni < 4; ni++) {
            const int ccol  = colBase + wc * 64 + ni * 16 + c;
            const int srow0 = rowBase + wr * 64 + mi * 16 + qr;
            if (mode == 0) {
                const int part = ccol >> 10;
                const int rem  = ccol & 1023;
                const int hh   = rem >> 6;
                const int dd   = rem & 63;
                if (part < 2) {
#pragma unroll
                    for (int r = 0; r < 4; r++)
                        ((ushort*)out)[((size_t)part * NH + hh) * S_LEN * HD +
                                       (size_t)(srow0 + r) * HD + dd] =
                            f32_to_bf16(acc[mi][ni][r]);
                } else {
                    // V: write transposed vt[h][d][s]; 4 consecutive s -> 8B store
                    ushort4v o;
#pragma unroll
                    for (int r = 0; r < 4; r++) o[r] = f32_to_bf16(acc[mi][ni][r]);
                    *(ushort4v*)(vt + ((size_t)hh * HD + dd) * S_LEN + srow0) = o;
                }
            } else if (outf) {
#pragma unroll
                for (int r = 0; r < 4; r++)
                    ((float*)out)[(size_t)(srow0 + r) * N + ccol] = acc[mi][ni][r];
            } else {
#pragma unroll
                for (int r = 0; r < 4; r++)
                    ((ushort*)out)[(size_t)(srow0 + r) * N + ccol] =
                        f32_to_bf16(acc[mi][ni][r]);
            }
        }
    }
}

// ---------------- MFMA block-sparse flash attention ----------------
#define PLD 72
__global__ __launch_bounds__(256) void attn_flash_k(const ushort* __restrict__ qkv,
                                                    const ushort* __restrict__ Vt,
                                                    ushort* __restrict__ attnout) {
    __shared__ ushort Plds[4][16 * PLD];

    const int wg   = blockIdx.x;        // 0..1023
    const int h    = wg >> 6;
    const int qb   = (wg & 63) * 64;
    const int wave = threadIdx.x >> 6;
    const int lane = threadIdx.x & 63;
    const int g    = lane >> 4;
    const int c    = lane & 15;

    const ushort* Qh  = qkv;
    const ushort* Kh  = qkv + (size_t)NH * S_LEN * HD;
    const ushort* Qhh = Qh + (size_t)h * S_LEN * HD;
    const ushort* Khh = Kh + (size_t)h * S_LEN * HD;
    const ushort* Vth = Vt + (size_t)h * HD * S_LEN;

    const int qrow0 = qb + wave * 16;

    short8 qf[2];
    qf[0] = *(const short8*)(Qhh + (size_t)(qrow0 + c) * HD + g * 8);
    qf[1] = *(const short8*)(Qhh + (size_t)(qrow0 + c) * HD + 32 + g * 8);

    floatx4 Oacc[4];
#pragma unroll
    for (int nd = 0; nd < 4; nd++) Oacc[nd] = (floatx4){0.f, 0.f, 0.f, 0.f};
    float mrow[4] = {-1e30f, -1e30f, -1e30f, -1e30f};
    float lrow[4] = {0.f, 0.f, 0.f, 0.f};

    int blist[4];
    int nb = 0;
    blist[nb++] = 0;
    int kbs = qb - 128; if (kbs < 64) kbs = 64;
    for (int kb = kbs; kb <= qb; kb += 64) blist[nb++] = kb;

    ushort* pl = &Plds[wave][0];

    for (int ib = 0; ib < nb; ib++) {
        const int kb = blist[ib];

        floatx4 sc[4];
#pragma unroll
        for (int t = 0; t < 4; t++) sc[t] = (floatx4){0.f, 0.f, 0.f, 0.f};
#pragma unroll
        for (int ks = 0; ks < 2; ks++) {
#pragma unroll
            for (int t = 0; t < 4; t++) {
                short8 kf = *(const short8*)(Khh + (size_t)(kb + 16 * t + c) * HD + ks * 32 + g * 8);
                sc[t] = __builtin_amdgcn_mfma_f32_16x16x32_bf16(qf[ks], kf, sc[t], 0, 0, 0);
            }
        }

#pragma unroll
        for (int t = 0; t < 4; t++) {
            const int j = kb + 16 * t + c;
#pragma unroll
            for (int r = 0; r < 4; r++) {
                const int qi = qrow0 + g * 4 + r;
                const bool ok = (j <= qi) && ((j >= qi - 128) || (j < 64));
                sc[t][r] = ok ? sc[t][r] * 0.125f : -1e30f;
            }
        }

#pragma unroll
        for (int r = 0; r < 4; r++) {
            float mx = fmaxf(fmaxf(sc[0][r], sc[1][r]), fmaxf(sc[2][r], sc[3][r]));
#pragma unroll
            for (int msk = 1; msk < 16; msk <<= 1) mx = fmaxf(mx, __shfl_xor(mx, msk, 64));
            const float mnew  = fmaxf(mrow[r], mx);
            const float alpha = __expf(mrow[r] - mnew);
            float psum = 0.f;
#pragma unroll
            for (int t = 0; t < 4; t++) {
                const float p = __expf(sc[t][r] - mnew);
                sc[t][r] = p;
                psum += p;
            }
#pragma unroll
            for (int msk = 1; msk < 16; msk <<= 1) psum += __shfl_xor(psum, msk, 64);
            lrow[r] = lrow[r] * alpha + psum;
            mrow[r] = mnew;
#pragma unroll
            for (int nd = 0; nd < 4; nd++) Oacc[nd][r] *= alpha;
        }

#pragma unroll
        for (int t = 0; t < 4; t++)
#pragma unroll
            for (int r = 0; r < 4; r++)
                pl[(g * 4 + r) * PLD + 16 * t + c] = f32_to_bf16(sc[t][r]);
        __syncthreads();

#pragma unroll
        for (int ks = 0; ks < 2; ks++) {
            short8 pf = *(const short8*)(pl + c * PLD + ks * 32 + g * 8);
#pragma unroll
            for (int nd = 0; nd < 4; nd++) {
                short8 vf = *(const short8*)(Vth + (size_t)(16 * nd + c) * S_LEN + kb + ks * 32 + g * 8);
                Oacc[nd] = __builtin_amdgcn_mfma_f32_16x16x32_bf16(pf, vf, Oacc[nd], 0, 0, 0);
            }
        }
        __syncthreads();
    }

#pragma unroll
    for (int r = 0; r < 4; r++) {
        const float inv = 1.0f / lrow[r];
        const int qi = qrow0 + g * 4 + r;
#pragma unroll
        for (int nd = 0; nd < 4; nd++)
            attnout[(size_t)qi * DIM + h * HD + 16 * nd + c] = f32_to_bf16(Oacc[nd][r] * inv);
    }
}

// ---------------- launch ----------------
extern "C" void kernel_launch(void* const* d_in, const int* in_sizes, int n_in,
                              void* d_out, int out_size, void* d_ws, size_t ws_size,
                              hipStream_t stream) {
    const void* x    = d_in[0];   // [S, DIM]
    const void* wqkv = d_in[1];   // [DIM, 3*NH*HD]
    const void* wout = d_in[2];   // [DIM, DIM]

    ushort* ws    = (ushort*)d_ws;
    ushort* xb    = ws;                                   // [S, DIM] bf16
    ushort* wqkvT = xb + (size_t)S_LEN * DIM;             // [NQKV, DIM]
    ushort* woutT = wqkvT + (size_t)NQKV * DIM;           // [DIM, DIM]
    ushort* qkv   = woutT + (size_t)DIM * DIM;            // [3][NH][S][HD] (V slot unused)
    ushort* attno = qkv + (size_t)3 * NH * S_LEN * HD;    // [S, DIM]
    ushort* vt    = attno + (size_t)S_LEN * DIM;          // [NH][HD][S]
    int* cntp     = (int*)(vt + (size_t)NH * HD * S_LEN);

    hipMemsetAsync(cntp, 0, sizeof(int), stream);
    detect_k<<<64, 256, 0, stream>>>((const ushort*)x, cntp);

    convert_x<<<(S_LEN * DIM / 8 + 255) / 256, 256, 0, stream>>>(x, xb, cntp);
    convt_k<<<dim3(NQKV / 32, DIM / 32), 256, 0, stream>>>(wqkv, wqkvT, DIM, NQKV, cntp);
    convt_k<<<dim3(DIM / 32, DIM / 32), 256, 0, stream>>>(wout, woutT, DIM, DIM, cntp);

    gemm_lds<<<dim3(NQKV / 128, S_LEN / 128), 256, 0, stream>>>(
        xb, wqkvT, qkv, vt, S_LEN, NQKV, DIM, 0, cntp);

    attn_flash_k<<<dim3(NH * (S_LEN / 64)), 256, 0, stream>>>(qkv, vt, attno);

    gemm_lds<<<dim3(DIM / 128, S_LEN / 128), 256, 0, stream>>>(
        attno, woutT, d_out, nullptr, S_LEN, DIM, DIM, 1, cntp);
}